// Round 4
// baseline (515.348 us; speedup 1.0000x reference)
//
#include <hip/hip_runtime.h>
#include <stdint.h>

#define NB   4096
#define DIN  1024
#define DOUT 1024
#define NL   32
#define KPW  (DIN * NL)     // 32768
#define KTOT (KPW + 64)     // 32832 (pad: 32 bias cols + 32 zero cols)
#define BKT  64
#define NSPLIT 4            // split-K ways: 129+128+128+128

typedef __attribute__((ext_vector_type(8))) short short8;          // 8 bf16
typedef __attribute__((ext_vector_type(8))) unsigned short ushort8;
typedef __attribute__((ext_vector_type(4))) float floatx4;         // C/D frag

__device__ __forceinline__ unsigned short f2bf(float v) {
    uint32_t u = __float_as_uint(v);
    return (unsigned short)((u + 0x7FFFu + ((u >> 16) & 1u)) >> 16);
}

__device__ __forceinline__ uint32_t f2bf2(float a, float b) {
    uint32_t ua = __float_as_uint(a), ub = __float_as_uint(b);
    ua += 0x7FFFu + ((ua >> 16) & 1u);
    ub += 0x7FFFu + ((ub >> 16) & 1u);
    return __builtin_amdgcn_perm(ub, ua, 0x07060302u);
}

__device__ __forceinline__ void async_ld16(const void* g, void* l) {
    __builtin_amdgcn_global_load_lds(
        (const __attribute__((address_space(1))) void*)g,
        (__attribute__((address_space(3))) void*)l, 16, 0, 0);
}

// ===========================================================================
// NEW PATH (needs ws >= pwb 67.2MB + y 269MB)
// ===========================================================================

// prep_y: role 1: pw fp32 -> bf16 pwb (as before). role 2: gating softmax
// (in-block) + materialize y[b, i*32+l] = bf16(x[b,i]*g[b,l]); i=1024 row of
// ones pairs with pwb's bias cols; i=1025 zero pad. role 3: zero C.
__global__ __launch_bounds__(256) void prep_y(
    const float* __restrict__ x, const float* __restrict__ gw,
    const float* __restrict__ gb, const float* __restrict__ pw,
    const float* __restrict__ pb, unsigned short* __restrict__ y,
    unsigned short* __restrict__ pwb, float* __restrict__ C)
{
    const int id = blockIdx.x;
    const int t  = threadIdx.x;

    if (id < DOUT) {
        const int o = id;
        const float* src = pw + (size_t)o * KPW;
        unsigned short* dst = pwb + (size_t)o * KTOT;
        #pragma unroll 2
        for (int s = 0; s < 16; ++s) {
            const int k = (s * 256 + t) * 8;
            const float4 a = *(const float4*)(src + k);
            const float4 c = *(const float4*)(src + k + 4);
            ushort8 o8;
            o8[0] = f2bf(a.x); o8[1] = f2bf(a.y); o8[2] = f2bf(a.z); o8[3] = f2bf(a.w);
            o8[4] = f2bf(c.x); o8[5] = f2bf(c.y); o8[6] = f2bf(c.z); o8[7] = f2bf(c.w);
            *(ushort8*)(dst + k) = o8;
        }
        if (t < 8) {
            ushort8 o8;
            #pragma unroll
            for (int j = 0; j < 8; ++j) {
                const int l = t * 8 + j;
                o8[j] = (l < NL) ? f2bf(pb[(size_t)o * NL + l]) : (unsigned short)0;
            }
            *(ushort8*)(dst + KPW + t * 8) = o8;
        }
    } else if (id < DOUT + NB / 4) {
        __shared__ float gsh[4][NL];
        const int wave = t >> 6;
        const int lane = t & 63;
        const int b0 = (id - DOUT) * 4;
        {   // gating softmax: one wave per row
            const int b = b0 + wave;
            const int l = lane & 31;
            const int c = lane >> 5;
            const float* xrow = x + (size_t)b * DIN;
            float p0 = 0.f, p1 = 0.f, p2 = 0.f, p3 = 0.f;
            const int i0 = c * 512;
            #pragma unroll 2
            for (int j = 0; j < 512; j += 4) {
                const int i = i0 + j;
                p0 = fmaf(xrow[i + 0], gw[(i + 0) * NL + l], p0);
                p1 = fmaf(xrow[i + 1], gw[(i + 1) * NL + l], p1);
                p2 = fmaf(xrow[i + 2], gw[(i + 2) * NL + l], p2);
                p3 = fmaf(xrow[i + 3], gw[(i + 3) * NL + l], p3);
            }
            float p = (p0 + p1) + (p2 + p3);
            p += __shfl_xor(p, 32);
            const float logit = p + gb[l];
            float m = logit;
            for (int off = 16; off > 0; off >>= 1) m = fmaxf(m, __shfl_xor(m, off));
            const float e = __expf(logit - m);
            float s = e;
            for (int off = 16; off > 0; off >>= 1) s += __shfl_xor(s, off);
            if (lane < NL) gsh[wave][l] = e / s;
        }
        __syncthreads();
        // y build: thread covers i-segments t, t+256, ... (32 bf16 each)
        #pragma unroll 1
        for (int rr = 0; rr < 4; ++rr) {
            const int b = b0 + rr;
            const float* xrow = x + (size_t)b * DIN;
            unsigned short* yrow = y + (size_t)b * KTOT;
            float gv[NL];
            #pragma unroll
            for (int l = 0; l < NL; ++l) gv[l] = gsh[rr][l];
            for (int i = t; i < KTOT / 32; i += 256) {  // 1026 segments
                const float xv = (i < DIN) ? xrow[i] : (i == DIN ? 1.0f : 0.0f);
                #pragma unroll
                for (int cq = 0; cq < 4; ++cq) {        // static gv indexing
                    ushort8 o8;
                    #pragma unroll
                    for (int jj = 0; jj < 8; ++jj)
                        o8[jj] = f2bf(xv * gv[cq * 8 + jj]);
                    *(ushort8*)(yrow + (size_t)i * 32 + cq * 8) = o8;
                }
            }
        }
    } else {
        const int zb = id - (DOUT + NB / 4);
        float4* dst = (float4*)C + (size_t)zb * (256 * 64) + t;
        const float4 z4 = {0.f, 0.f, 0.f, 0.f};
        #pragma unroll 4
        for (int s = 0; s < 64; ++s) dst[s * 256] = z4;
    }
}

// ---------------------------------------------------------------------------
// gemm_2buf: 256x256 tile, 8 waves, 4 phases/K-tile, BOTH operands via
// global_load_lds (pure-DMA: the regime the 8-phase template is proven in).
// 2 buffers/operand (128KB LDS, 1 block/CU). Derived waits:
//   group j reads tile j from buf[j&1], stages tile j+1 into buf[~j&1]
//   (freed at end of group j-1), 2 loads/phase in part order Aα,Bα,Aβ,Bβ.
//   ph1: vmcnt(2) -> prior group's ph3,4 (Aβ,Bβ of tile j) landed.
//   ph4: vmcnt(4) -> this group's ph1,2 (Aα,Bα of tile j+1) landed.
//   Never vmcnt(0), no lgkm pacing, no sched_barrier pins; bf-α held in
//   regs ph1->ph4 so ph4 issues zero ds_reads.
// Parts (α = data read in ph1, β in ph2/3) interleave 64/32-row groups so
// each wave's rows live in one region; chunk-XOR swizzle as r3 (source
// pre-swizzled, reads use slot&7 involution).
// Grid 256 = 64 (bm,z) combos x 4 bn; XCD decode gives each XCD 8 combos
// so the 4 bn-sharers of an A-panel hit one L2.
// ---------------------------------------------------------------------------
__global__ __launch_bounds__(512, 2) void gemm_2buf(
    const unsigned short* __restrict__ Ay,  // y   [NB][KTOT] bf16
    const unsigned short* __restrict__ Bw,  // pwb [DOUT][KTOT] bf16
    float* __restrict__ C)                  // [NB][DOUT], pre-zeroed
{
    __shared__ __align__(16) unsigned short Ash[2][16384];  // 64 KB
    __shared__ __align__(16) unsigned short Bsh[2][16384];  // 64 KB

    const int t    = threadIdx.x;
    const int wave = t >> 6;
    const int lane = t & 63;

    const int bid = blockIdx.x;
    const int xcd = bid & 7;
    const int loc = bid >> 3;              // 0..31
    const int q   = xcd * 8 + (loc >> 2);  // 0..63 = (bm,z) combo
    const int bn  = (loc & 3) * 256;
    const int bm  = (q & 15) * 256;
    const int z   = q >> 4;
    const int it0 = z * 128 + (z ? 1 : 0); // splits 129+128+128+128
    const int nt  = z ? 128 : 129;

    const int wr   = wave >> 2;            // 0..1
    const int wc   = wave & 3;             // 0..3
    const int ml   = lane & 15;
    const int quad = lane >> 4;
    const int xm   = ml & 7;
    const int sw0  = (quad ^ xm) * 8;      // kk=0 chunk (elems)
    const int sw1  = ((4 + quad) ^ xm) * 8;

    // staging: thread t -> slot (LDS row within 64-row load), chunk pos
    const int slot = t >> 3;               // 0..63
    const int sw   = ((t & 7) ^ (slot & 7)) * 8;  // pre-swizzled source chunk
    // A sources: loads cover rows bm+{slot, 128+slot | 64+slot, 192+slot}
    const unsigned short* a0 = Ay + (size_t)(bm +       slot) * KTOT + sw;
    const unsigned short* a1 = Ay + (size_t)(bm + 128 + slot) * KTOT + sw;
    const unsigned short* a2 = Ay + (size_t)(bm +  64 + slot) * KTOT + sw;
    const unsigned short* a3 = Ay + (size_t)(bm + 192 + slot) * KTOT + sw;
    // B sources: 32-row interleave (α: wc-cols 0-31, β: wc-cols 32-63)
    const int brow = (slot >> 5) * 64 + (slot & 31);
    const unsigned short* b0 = Bw + (size_t)(bn +       brow) * KTOT + sw;
    const unsigned short* b1 = Bw + (size_t)(bn + 128 + brow) * KTOT + sw;
    const unsigned short* b2 = Bw + (size_t)(bn +  32 + brow) * KTOT + sw;
    const unsigned short* b3 = Bw + (size_t)(bn + 160 + brow) * KTOT + sw;
    const int ldst = wave * 512;           // elems; HW adds lane*16B

    // read bases (elems)
    const int ai = (wr * 64 + ml) * 64;    // af: + im*1024 (+8192 for β)
    const int bi = (wc * 32 + ml) * 64;    // bf: + in*1024 (+8192 for β)

    floatx4 acc[8][4] = {};
    short8 af[8], bfa[4], bfb[4];

    // ---- prologue: stage tile it0 fully into buf0; one-time full drain ----
    {
        const size_t ko = (size_t)it0 * BKT;
        async_ld16(a0 + ko, &Ash[0][ldst]);
        async_ld16(a1 + ko, &Ash[0][ldst +  4096]);
        async_ld16(b0 + ko, &Bsh[0][ldst]);
        async_ld16(b1 + ko, &Bsh[0][ldst +  4096]);
        async_ld16(a2 + ko, &Ash[0][ldst +  8192]);
        async_ld16(a3 + ko, &Ash[0][ldst + 12288]);
        async_ld16(b2 + ko, &Bsh[0][ldst +  8192]);
        async_ld16(b3 + ko, &Bsh[0][ldst + 12288]);
    }
    asm volatile("s_waitcnt vmcnt(0)" ::: "memory");
    __builtin_amdgcn_s_barrier();

    for (int j = 0; j < nt; ++j) {
        const int rb = j & 1, sb = rb ^ 1;
        const unsigned short* aR = &Ash[rb][0];
        const unsigned short* bR = &Bsh[rb][0];
        const size_t ko = (size_t)(it0 + ((j + 1 < nt) ? (j + 1) : (nt - 1))) * BKT;

        // ---- ph1: stage Aα(next) | read afα+bfα | vmcnt(2) | q(im0-3,in0-1)
        async_ld16(a0 + ko, &Ash[sb][ldst]);
        async_ld16(a1 + ko, &Ash[sb][ldst + 4096]);
        #pragma unroll
        for (int im = 0; im < 4; ++im) {
            af[im*2+0] = *(const short8*)(aR + ai + im*1024 + sw0);
            af[im*2+1] = *(const short8*)(aR + ai + im*1024 + sw1);
        }
        #pragma unroll
        for (int in = 0; in < 2; ++in) {
            bfa[in*2+0] = *(const short8*)(bR + bi + in*1024 + sw0);
            bfa[in*2+1] = *(const short8*)(bR + bi + in*1024 + sw1);
        }
        asm volatile("s_waitcnt vmcnt(2)" ::: "memory");
        __builtin_amdgcn_s_barrier();
        __builtin_amdgcn_s_setprio(1);
        #pragma unroll
        for (int im = 0; im < 4; ++im)
            #pragma unroll
            for (int in = 0; in < 2; ++in) {
                acc[im][in] = __builtin_amdgcn_mfma_f32_16x16x32_bf16(
                    af[im*2+0], bfa[in*2+0], acc[im][in], 0, 0, 0);
                acc[im][in] = __builtin_amdgcn_mfma_f32_16x16x32_bf16(
                    af[im*2+1], bfa[in*2+1], acc[im][in], 0, 0, 0);
            }
        __builtin_amdgcn_s_setprio(0);
        __builtin_amdgcn_s_barrier();

        // ---- ph2: stage Bα(next) | read bfβ | q(im0-3,in2-3) ----
        async_ld16(b0 + ko, &Bsh[sb][ldst]);
        async_ld16(b1 + ko, &Bsh[sb][ldst + 4096]);
        #pragma unroll
        for (int in = 0; in < 2; ++in) {
            bfb[in*2+0] = *(const short8*)(bR + 8192 + bi + in*1024 + sw0);
            bfb[in*2+1] = *(const short8*)(bR + 8192 + bi + in*1024 + sw1);
        }
        __builtin_amdgcn_s_barrier();
        __builtin_amdgcn_s_setprio(1);
        #pragma unroll
        for (int im = 0; im < 4; ++im)
            #pragma unroll
            for (int in = 0; in < 2; ++in) {
                acc[im][in+2] = __builtin_amdgcn_mfma_f32_16x16x32_bf16(
                    af[im*2+0], bfb[in*2+0], acc[im][in+2], 0, 0, 0);
                acc[im][in+2] = __builtin_amdgcn_mfma_f32_16x16x32_bf16(
                    af[im*2+1], bfb[in*2+1], acc[im][in+2], 0, 0, 0);
            }
        __builtin_amdgcn_s_setprio(0);
        __builtin_amdgcn_s_barrier();

        // ---- ph3: stage Aβ(next) | read afβ | q(im4-7,in2-3) ----
        async_ld16(a2 + ko, &Ash[sb][ldst +  8192]);
        async_ld16(a3 + ko, &Ash[sb][ldst + 12288]);
        #pragma unroll
        for (int im = 0; im < 4; ++im) {
            af[im*2+0] = *(const short8*)(aR + 8192 + ai + im*1024 + sw0);
            af[im*2+1] = *(const short8*)(aR + 8192 + ai + im*1024 + sw1);
        }
        __builtin_amdgcn_s_barrier();
        __builtin_amdgcn_s_setprio(1);
        #pragma unroll
        for (int im = 0; im < 4; ++im)
            #pragma unroll
            for (int in = 0; in < 2; ++in) {
                acc[im+4][in+2] = __builtin_amdgcn_mfma_f32_16x16x32_bf16(
                    af[im*2+0], bfb[in*2+0], acc[im+4][in+2], 0, 0, 0);
                acc[im+4][in+2] = __builtin_amdgcn_mfma_f32_16x16x32_bf16(
                    af[im*2+1], bfb[in*2+1], acc[im+4][in+2], 0, 0, 0);
            }
        __builtin_amdgcn_s_setprio(0);
        __builtin_amdgcn_s_barrier();

        // ---- ph4: stage Bβ(next) | NO reads (bfa held) | vmcnt(4) | q(im4-7,in0-1)
        async_ld16(b2 + ko, &Bsh[sb][ldst +  8192]);
        async_ld16(b3 + ko, &Bsh[sb][ldst + 12288]);
        asm volatile("s_waitcnt vmcnt(4)" ::: "memory");
        __builtin_amdgcn_s_barrier();
        __builtin_amdgcn_s_setprio(1);
        #pragma unroll
        for (int im = 0; im < 4; ++im)
            #pragma unroll
            for (int in = 0; in < 2; ++in) {
                acc[im+4][in] = __builtin_amdgcn_mfma_f32_16x16x32_bf16(
                    af[im*2+0], bfa[in*2+0], acc[im+4][in], 0, 0, 0);
                acc[im+4][in] = __builtin_amdgcn_mfma_f32_16x16x32_bf16(
                    af[im*2+1], bfa[in*2+1], acc[im+4][in], 0, 0, 0);
            }
        __builtin_amdgcn_s_setprio(0);
        __builtin_amdgcn_s_barrier();
    }

    // epilogue: C/D map col=lane&15, row=quad*4+reg; im*16 / in*16 are the
    // clean row/col offsets for both α (0-3/0-1) and β (4-7/2-3) groups.
    #pragma unroll
    for (int im = 0; im < 8; ++im)
        #pragma unroll
        for (int in = 0; in < 4; ++in) {
            const int row = bm + wr * 128 + im * 16 + quad * 4;
            const int col = bn + wc * 64 + in * 16 + ml;
            #pragma unroll
            for (int rr = 0; rr < 4; ++rr)
                atomicAdd(&C[(size_t)(row + rr) * DOUT + col], acc[im][in][rr]);
        }
}

// ===========================================================================
// FALLBACK PATH (exact r0/r3 proven kernels, 357us total) — used when the
// workspace can't hold y (needs 337MB).
// ===========================================================================
__global__ __launch_bounds__(256) void prep_fused(
    const float* __restrict__ x, const float* __restrict__ gw,
    const float* __restrict__ gb, const float* __restrict__ pw,
    const float* __restrict__ pb, float* __restrict__ g,
    unsigned short* __restrict__ pwb, float* __restrict__ C)
{
    const int id = blockIdx.x;
    const int t  = threadIdx.x;

    if (id < DOUT) {
        const int o = id;
        const float* src = pw + (size_t)o * KPW;
        unsigned short* dst = pwb + (size_t)o * KTOT;
        #pragma unroll 2
        for (int s = 0; s < 16; ++s) {
            const int k = (s * 256 + t) * 8;
            const float4 a = *(const float4*)(src + k);
            const float4 c = *(const float4*)(src + k + 4);
            ushort8 o8;
            o8[0] = f2bf(a.x); o8[1] = f2bf(a.y); o8[2] = f2bf(a.z); o8[3] = f2bf(a.w);
            o8[4] = f2bf(c.x); o8[5] = f2bf(c.y); o8[6] = f2bf(c.z); o8[7] = f2bf(c.w);
            *(ushort8*)(dst + k) = o8;
        }
        if (t < 8) {
            ushort8 o8;
            #pragma unroll
            for (int j = 0; j < 8; ++j) {
                const int l = t * 8 + j;
                o8[j] = (l < NL) ? f2bf(pb[(size_t)o * NL + l]) : (unsigned short)0;
            }
            *(ushort8*)(dst + KPW + t * 8) = o8;
        }
    } else if (id < DOUT + NB / 4) {
        const int wave = t >> 6;
        const int lane = t & 63;
        const int b = (id - DOUT) * 4 + wave;
        const int l = lane & 31;
        const int c = lane >> 5;
        const float* xrow = x + (size_t)b * DIN;
        float p0 = 0.f, p1 = 0.f, p2 = 0.f, p3 = 0.f;
        const int i0 = c * 512;
        #pragma unroll 2
        for (int j = 0; j < 512; j += 4) {
            const int i = i0 + j;
            p0 = fmaf(xrow[i + 0], gw[(i + 0) * NL + l], p0);
            p1 = fmaf(xrow[i + 1], gw[(i + 1) * NL + l], p1);
            p2 = fmaf(xrow[i + 2], gw[(i + 2) * NL + l], p2);
            p3 = fmaf(xrow[i + 3], gw[(i + 3) * NL + l], p3);
        }
        float p = (p0 + p1) + (p2 + p3);
        p += __shfl_xor(p, 32);
        const float logit = p + gb[l];
        float m = logit;
        for (int off = 16; off > 0; off >>= 1) m = fmaxf(m, __shfl_xor(m, off));
        const float e = __expf(logit - m);
        float s = e;
        for (int off = 16; off > 0; off >>= 1) s += __shfl_xor(s, off);
        if (lane < NL) g[(size_t)b * NL + l] = e / s;
    } else {
        const int zb = id - (DOUT + NB / 4);
        float4* dst = (float4*)C + (size_t)zb * (256 * 64) + t;
        const float4 z4 = {0.f, 0.f, 0.f, 0.f};
        #pragma unroll 4
        for (int s = 0; s < 64; ++s) dst[s * 256] = z4;
    }
}

__global__ __launch_bounds__(256, 4) void gemm_splitk(
    const float* __restrict__ X, const float* __restrict__ G,
    const unsigned short* __restrict__ Bw, float* __restrict__ C)
{
    __shared__ unsigned short As[128 * BKT];
    __shared__ unsigned short Bs[128 * BKT];

    const int t    = threadIdx.x;
    const int wave = t >> 6;
    const int lane = t & 63;

    const int id  = blockIdx.x;
    const int xcd = id & 7;
    const int s_  = id >> 3;
    const int bn  = (s_ & 7) * 128;
    const int idx = xcd * 16 + (s_ >> 3);
    const int bm  = (idx & 31) * 128;
    const int z   = idx >> 5;
    const int it0 = z * 128 + (z ? 1 : 0);
    const int it1 = (z + 1) * 128 + 1;

    const int wm   = (wave >> 1) * 64;
    const int wn   = (wave & 1) * 64;
    const int ml   = lane & 15;
    const int quad = lane >> 4;
    const int xorm = ml & 7;

    const int row0 = t >> 3;
    const int uc   = (((t & 7) ^ ((t >> 3) & 7)) * 8);
    const unsigned short* Bg = Bw + (size_t)(bn + row0) * KTOT + uc + (size_t)it0 * BKT;
    unsigned short* Bl = Bs + wave * 512;

    const int r   = t >> 1;
    const int lh  = (t & 1) * 16;
    const int rx  = r & 7;
    const float* xp = X + (size_t)(bm + r) * DIN;
    unsigned short* Aw = As + r * BKT;
    float gq[16];
    {
        const float* gp = G + (size_t)(bm + r) * NL + lh;
        #pragma unroll
        for (int qq = 0; qq < 4; ++qq) {
            const float4 v = *(const float4*)(gp + qq * 4);
            gq[qq * 4 + 0] = v.x; gq[qq * 4 + 1] = v.y;
            gq[qq * 4 + 2] = v.z; gq[qq * 4 + 3] = v.w;
        }
    }

    floatx4 acc[4][4] = {};
    float2 xv = *(const float2*)(xp + min(it0 * 2, DIN - 2));

    for (int it = it0; it < it1; ++it) {
        #pragma unroll
        for (int s = 0; s < 4; ++s)
            async_ld16(Bg + (size_t)(s * 32) * KTOT, Bl + s * 2048);
        Bg += BKT;

        const bool inb = (it * 2) < DIN;
        const float xa = inb ? xv.x : 1.0f;
        const float xb = inb ? xv.y : 0.0f;
        xv = *(const float2*)(xp + min((it + 1) * 2, DIN - 2));

        #pragma unroll
        for (int ii = 0; ii < 2; ++ii) {
            const float xs = ii ? xb : xa;
            #pragma unroll
            for (int jj = 0; jj < 2; ++jj) {
                uint4 v;
                v.x = f2bf2(xs * gq[jj * 8 + 0], xs * gq[jj * 8 + 1]);
                v.y = f2bf2(xs * gq[jj * 8 + 2], xs * gq[jj * 8 + 3]);
                v.z = f2bf2(xs * gq[jj * 8 + 4], xs * gq[jj * 8 + 5]);
                v.w = f2bf2(xs * gq[jj * 8 + 6], xs * gq[jj * 8 + 7]);
                const int c = ii * 4 + (t & 1) * 2 + jj;
                *(uint4*)(Aw + ((c ^ rx) * 8)) = v;
            }
        }
        __syncthreads();

        #pragma unroll
        for (int kk = 0; kk < 2; ++kk) {
            const int swz = ((kk * 4 + quad) ^ xorm) * 8;
            short8 afr[4], bfr[4];
            #pragma unroll
            for (int im = 0; im < 4; ++im)
                afr[im] = *(const short8*)(As + (wm + im * 16 + ml) * BKT + swz);
            #pragma unroll
            for (int in = 0; in < 4; ++in)
                bfr[in] = *(const short8*)(Bs + (wn + in * 16 + ml) * BKT + swz);
            #pragma unroll
            for (int im = 0; im < 4; ++im)
                #pragma unroll
                for (int in = 0; in < 4; ++in)
                    acc[im][in] = __builtin_amdgcn_mfma_f32_16x16x32_bf16(
                        afr[im], bfr[in], acc[im][in], 0, 0, 0);
        }
        __syncthreads();
    }

    #pragma unroll
    for (int im = 0; im < 4; ++im)
        #pragma unroll
        for (int in = 0; in < 4; ++in) {
            const int row = bm + wm + im * 16 + quad * 4;
            const int col = bn + wn + in * 16 + ml;
            #pragma unroll
            for (int rr = 0; rr < 4; ++rr)
                atomicAdd(&C[(size_t)(row + rr) * DOUT + col], acc[im][in][rr]);
        }
}

// ---------------------------------------------------------------------------
extern "C" void kernel_launch(void* const* d_in, const int* in_sizes, int n_in,
                              void* d_out, int out_size, void* d_ws, size_t ws_size,
                              hipStream_t stream) {
    const float* x  = (const float*)d_in[0];
    const float* gw = (const float*)d_in[1];
    const float* gb = (const float*)d_in[2];
    const float* pw = (const float*)d_in[3];
    const float* pb = (const float*)d_in[4];
    float* out = (float*)d_out;

    const size_t pwb_bytes = (size_t)DOUT * KTOT * 2;   // 67,239,936
    const size_t y_bytes   = (size_t)NB   * KTOT * 2;   // 268,959,744

    if (ws_size >= pwb_bytes + y_bytes) {
        unsigned short* pwb = (unsigned short*)d_ws;
        unsigned short* y   = (unsigned short*)((char*)d_ws + pwb_bytes);
        prep_y<<<DOUT + NB / 4 + 64, 256, 0, stream>>>(x, gw, gb, pw, pb, y, pwb, out);
        gemm_2buf<<<256, 512, 0, stream>>>(y, pwb, out);
    } else {
        float* g            = (float*)d_ws;
        unsigned short* pwb = (unsigned short*)((char*)d_ws + (1 << 20));
        prep_fused<<<DOUT + NB / 4 + 64, 256, 0, stream>>>(x, gw, gb, pw, pb, g, pwb, out);
        gemm_splitk<<<(DOUT / 128) * (NB / 128) * NSPLIT, 256, 0, stream>>>(x, g, pwb, out);
    }
}

// Round 5
// 356.406 us; speedup vs baseline: 1.4460x; 1.4460x over previous
//
#include <hip/hip_runtime.h>
#include <stdint.h>

// ===========================================================================
// SESSION LEDGER (do not retry without new information):
//  r0  (this kernel): prep_fused + 128x128 splitK=4 GEMM    -> 357.5us TOTAL
//      (GEMM 311-320us, 886 TF, MfmaUtil 42%, VALUBusy 51%, occ 39%).
//  r7  256^2 8-wave 4-phase, A built in P4, 3-buf B          -> 445 (GEMM 425)
//  r8  same + dbuf A/B, derived waits, 2-deep x pipeline     -> 427 (GEMM 409)
//  r9  r3 structure + dbuf B + counted vmcnt + sched_barrier -> 457 (GEMM 447;
//      m141 failure mode: VGPR 64->112, occ 39->23)
//  r10 256^2 pure-DMA both operands (y materialized, 337MB ws)-> 515 (GEMM 388;
//      VALUBusy 11%, conflicts 0, MfmaUtil 30% -> phase-lockstep barrier gaps
//      at 1 block/CU are the structural cost, NOT A-build/waits/conflicts).
//  Conclusion: m201-style 8-phase does not reproduce from scratch in plain
//  HIP here (matches m232 precedent). 275.5 GFLOP is algebraically minimal;
//  fp8/MX risks absmax. This kernel = best known config; plateau is the
//  documented m97-structure ~900TF ceiling (42% MfmaUtil, TLP-hidden).
// ===========================================================================

#define NB   4096
#define DIN  1024
#define DOUT 1024
#define NL   32
#define KPW  (DIN * NL)     // 32768
#define KTOT (KPW + 64)     // 32832 (pad: 32 bias cols + 32 zero cols)
#define BKT  64
#define KITERS (KTOT / BKT) // 513
#define NSPLIT 4            // split-K ways: 129+128+128+128 (r3 best: 311us)

typedef __attribute__((ext_vector_type(8))) short short8;          // 8 bf16 (A/B frag)
typedef __attribute__((ext_vector_type(8))) unsigned short ushort8;
typedef __attribute__((ext_vector_type(4))) float floatx4;         // C/D frag

// float -> bf16 bits, round-to-nearest-even (finite inputs only)
__device__ __forceinline__ unsigned short f2bf(float v) {
    uint32_t u = __float_as_uint(v);
    return (unsigned short)((u + 0x7FFFu + ((u >> 16) & 1u)) >> 16);
}

// two floats -> packed bf16x2 (RNE), low half = a (r3 config; r4's trunc pack
// regressed 311->326: A-build VALU is NOT on the critical path)
__device__ __forceinline__ uint32_t f2bf2(float a, float b) {
    uint32_t ua = __float_as_uint(a), ub = __float_as_uint(b);
    ua += 0x7FFFu + ((ua >> 16) & 1u);
    ub += 0x7FFFu + ((ub >> 16) & 1u);
    return __builtin_amdgcn_perm(ub, ua, 0x07060302u);  // {ub_hi16, ua_hi16}
}

// async global->LDS, 16B per lane; LDS dst = wave-uniform base + lane*16
__device__ __forceinline__ void async_ld16(const void* g, void* l) {
    __builtin_amdgcn_global_load_lds(
        (const __attribute__((address_space(1))) void*)g,
        (__attribute__((address_space(3))) void*)l, 16, 0, 0);
}

// ---------------------------------------------------------------------------
// Fused prep (ONE dispatch replaces memset + gate + build_pwb; r6):
//   blocks [0,1024)    : pw fp32 (+pb) -> bf16 pwb row
//   blocks [1024,2048) : gating softmax, 4 rows/block -> g fp32
//   blocks [2048,2112) : zero d_out (harness poisons it 0xAA each replay)
// Role branch is block-uniform. GEMM depends on all three via stream order.
// ---------------------------------------------------------------------------
__global__ __launch_bounds__(256) void prep_fused(
    const float* __restrict__ x, const float* __restrict__ gw,
    const float* __restrict__ gb, const float* __restrict__ pw,
    const float* __restrict__ pb, float* __restrict__ g,
    unsigned short* __restrict__ pwb, float* __restrict__ C)
{
    const int id = blockIdx.x;
    const int t  = threadIdx.x;

    if (id < DOUT) {
        // ---- role 1: pwb build (HBM-bound: 134MB read + 67MB write) ----
        const int o = id;
        const float* src = pw + (size_t)o * KPW;
        unsigned short* dst = pwb + (size_t)o * KTOT;
        #pragma unroll 2
        for (int s = 0; s < 16; ++s) {
            const int k = (s * 256 + t) * 8;
            const float4 a = *(const float4*)(src + k);
            const float4 c = *(const float4*)(src + k + 4);
            ushort8 o8;
            o8[0] = f2bf(a.x); o8[1] = f2bf(a.y); o8[2] = f2bf(a.z); o8[3] = f2bf(a.w);
            o8[4] = f2bf(c.x); o8[5] = f2bf(c.y); o8[6] = f2bf(c.z); o8[7] = f2bf(c.w);
            *(ushort8*)(dst + k) = o8;
        }
        if (t < 8) {   // tail: 32 bias cols + 32 zeros
            ushort8 o8;
            #pragma unroll
            for (int j = 0; j < 8; ++j) {
                const int l = t * 8 + j;
                o8[j] = (l < NL) ? f2bf(pb[(size_t)o * NL + l]) : (unsigned short)0;
            }
            *(ushort8*)(dst + KPW + t * 8) = o8;
        }
    } else if (id < DOUT + NB / 4) {
        // ---- role 2: gating softmax, one wave per row ----
        const int wave = t >> 6;
        const int lane = t & 63;
        const int b = (id - DOUT) * 4 + wave;
        const int l = lane & 31;
        const int c = lane >> 5;
        const float* xrow = x + (size_t)b * DIN;
        float p0 = 0.f, p1 = 0.f, p2 = 0.f, p3 = 0.f;
        const int i0 = c * 512;
        #pragma unroll 2
        for (int j = 0; j < 512; j += 4) {
            const int i = i0 + j;
            p0 = fmaf(xrow[i + 0], gw[(i + 0) * NL + l], p0);
            p1 = fmaf(xrow[i + 1], gw[(i + 1) * NL + l], p1);
            p2 = fmaf(xrow[i + 2], gw[(i + 2) * NL + l], p2);
            p3 = fmaf(xrow[i + 3], gw[(i + 3) * NL + l], p3);
        }
        float p = (p0 + p1) + (p2 + p3);
        p += __shfl_xor(p, 32);
        const float logit = p + gb[l];
        float m = logit;
        for (int off = 16; off > 0; off >>= 1) m = fmaxf(m, __shfl_xor(m, off));
        const float e = __expf(logit - m);
        float s = e;
        for (int off = 16; off > 0; off >>= 1) s += __shfl_xor(s, off);
        if (lane < NL) g[(size_t)b * NL + l] = e / s;
    } else {
        // ---- role 3: zero C (16MB / 64 blocks = 64 float4-iters/thread) ----
        const int zb = id - (DOUT + NB / 4);
        float4* dst = (float4*)C + (size_t)zb * (256 * 64) + t;
        const float4 z4 = {0.f, 0.f, 0.f, 0.f};
        #pragma unroll 4
        for (int s = 0; s < 64; ++s) dst[s * 256] = z4;
    }
}

// ---------------------------------------------------------------------------
// GEMM (exact r3 config — best measured: 311us, 886 TF, at the documented
// m97-structure plateau): C[b,o] += sum_k y[b,k]*pwb[o,k], y built on the fly
// in LDS (y[b,i*32+l] = bf16(x[b,i]*g[b,l]); bias iter i=1024 uses x==1).
// 128x128 tile, BK=64, split-K=4, XOR-swizzled LDS (r2: conflicts 1e8->0).
// Register budget: 64 VGPR + 64 AGPR = 128 -> 4 waves/SIMD -> 4 blocks/CU
// hard cap (r5 lesson: grid/split-K can't raise occupancy past this).
// DO NOT: add asm waits/sched_barriers (r9), double-buffer (r9), or move to
// 256^2 phases (r7/r8/r10) — all measured worse; see ledger at top.
// ---------------------------------------------------------------------------
__global__ __launch_bounds__(256, 4) void gemm_splitk(
    const float* __restrict__ X,            // x [NB][DIN] fp32
    const float* __restrict__ G,            // g [NB][NL]  fp32
    const unsigned short* __restrict__ Bw,  // pwb [DOUT][KTOT] bf16
    float* __restrict__ C)                  // [NB][DOUT], pre-zeroed
{
    __shared__ unsigned short As[128 * BKT];
    __shared__ unsigned short Bs[128 * BKT];

    const int t    = threadIdx.x;
    const int wave = t >> 6;
    const int lane = t & 63;

    // XCD-aware decode: 8 bn-blocks sharing one (bm,z) A-panel -> same XCD L2
    const int id  = blockIdx.x;
    const int xcd = id & 7;
    const int s_  = id >> 3;               // 0..127
    const int bn  = (s_ & 7) * 128;
    const int idx = xcd * 16 + (s_ >> 3);  // 0..127
    const int bm  = (idx & 31) * 128;
    const int z   = idx >> 5;              // 0..3
    const int it0 = z * 128 + (z ? 1 : 0); // splits: 129+128+128+128
    const int it1 = (z + 1) * 128 + 1;

    const int wm = (wave >> 1) * 64;
    const int wn = (wave & 1) * 64;
    const int ml   = lane & 15;
    const int quad = lane >> 4;
    const int xorm = ml & 7;

    // B staging via async DMA (swizzled source, as r2)
    const int row0 = t >> 3;
    const int uc   = (((t & 7) ^ ((t >> 3) & 7)) * 8);
    const unsigned short* Bg = Bw + (size_t)(bn + row0) * KTOT + uc + (size_t)it0 * BKT;
    unsigned short* Bl = Bs + wave * 512;   // + s*2048 per chunk; HW adds lane*16B

    // A on-the-fly build: thread t owns row r=t>>1, leaves lh=(t&1)*16..+15
    const int r   = t >> 1;                 // row 0..127
    const int lh  = (t & 1) * 16;           // leaf base 0 or 16
    const int rx  = r & 7;
    const float* xp = X + (size_t)(bm + r) * DIN;
    unsigned short* Aw = As + r * BKT;
    float gq[16];
    {
        const float* gp = G + (size_t)(bm + r) * NL + lh;
        #pragma unroll
        for (int q = 0; q < 4; ++q) {
            const float4 v = *(const float4*)(gp + q * 4);
            gq[q * 4 + 0] = v.x; gq[q * 4 + 1] = v.y;
            gq[q * 4 + 2] = v.z; gq[q * 4 + 3] = v.w;
        }
    }

    floatx4 acc[4][4] = {};
    float2 xv = *(const float2*)(xp + min(it0 * 2, DIN - 2));

    for (int it = it0; it < it1; ++it) {
        // 1) B tile DMA (overlaps the VALU A-build below)
        #pragma unroll
        for (int s = 0; s < 4; ++s)
            async_ld16(Bg + (size_t)(s * 32) * KTOT, Bl + s * 2048);
        Bg += BKT;

        // 2) bias fixup (uniform branch; only it==512 hits it)
        const bool inb = (it * 2) < DIN;
        const float xa = inb ? xv.x : 1.0f;   // i=1024: y-col = g (pairs with pb)
        const float xb = inb ? xv.y : 0.0f;   // i=1025: zero pad
        // 3) prefetch next x (clamped; drained by the same pre-barrier wait)
        xv = *(const float2*)(xp + min((it + 1) * 2, DIN - 2));

        // 4) build 32 bf16 of As: rows fixed, chunks c = ii*4 + (t&1)*2 + j
        #pragma unroll
        for (int ii = 0; ii < 2; ++ii) {
            const float xs = ii ? xb : xa;
            #pragma unroll
            for (int j = 0; j < 2; ++j) {
                uint4 v;
                v.x = f2bf2(xs * gq[j * 8 + 0], xs * gq[j * 8 + 1]);
                v.y = f2bf2(xs * gq[j * 8 + 2], xs * gq[j * 8 + 3]);
                v.z = f2bf2(xs * gq[j * 8 + 4], xs * gq[j * 8 + 5]);
                v.w = f2bf2(xs * gq[j * 8 + 6], xs * gq[j * 8 + 7]);
                const int c = ii * 4 + (t & 1) * 2 + j;
                *(uint4*)(Aw + ((c ^ rx) * 8)) = v;
            }
        }
        __syncthreads();

        #pragma unroll
        for (int kk = 0; kk < 2; ++kk) {
            const int swz = ((kk * 4 + quad) ^ xorm) * 8;
            short8 af[4], bf[4];
            #pragma unroll
            for (int im = 0; im < 4; ++im)
                af[im] = *(const short8*)(As + (wm + im * 16 + ml) * BKT + swz);
            #pragma unroll
            for (int in = 0; in < 4; ++in)
                bf[in] = *(const short8*)(Bs + (wn + in * 16 + ml) * BKT + swz);
            #pragma unroll
            for (int im = 0; im < 4; ++im)
                #pragma unroll
                for (int in = 0; in < 4; ++in)
                    acc[im][in] = __builtin_amdgcn_mfma_f32_16x16x32_bf16(
                        af[im], bf[in], acc[im][in], 0, 0, 0);
        }
        __syncthreads();
    }

    // epilogue: C/D map col=lane&15, row=quad*4+reg (m89-verified); atomic for split-K
    #pragma unroll
    for (int im = 0; im < 4; ++im)
        #pragma unroll
        for (int in = 0; in < 4; ++in) {
            const int row = bm + wm + im * 16 + quad * 4;
            const int col = bn + wn + in * 16 + ml;
            #pragma unroll
            for (int rr = 0; rr < 4; ++rr)
                atomicAdd(&C[(size_t)(row + rr) * DOUT + col], acc[im][in][rr]);
        }
}

// ---------------------------------------------------------------------------
extern "C" void kernel_launch(void* const* d_in, const int* in_sizes, int n_in,
                              void* d_out, int out_size, void* d_ws, size_t ws_size,
                              hipStream_t stream) {
    const float* x  = (const float*)d_in[0];   // [4096,1024]
    const float* gw = (const float*)d_in[1];   // [1024,32]
    const float* gb = (const float*)d_in[2];   // [32]
    const float* pw = (const float*)d_in[3];   // [1024,1024,32]
    const float* pb = (const float*)d_in[4];   // [1024,32]
    float* out = (float*)d_out;                // [4096,1024]

    float* g            = (float*)d_ws;                               // 512 KB
    unsigned short* pwb = (unsigned short*)((char*)d_ws + (1 << 20)); // 67.2 MB
    // ws use: 1 MB + 1024*32832*2 = ~68.3 MB

    // One fused prep dispatch: pwb (1024 blocks) + gate (1024) + zero-C (64)
    prep_fused<<<DOUT + NB / 4 + 64, 256, 0, stream>>>(x, gw, gb, pw, pb, g, pwb, out);
    gemm_splitk<<<(DOUT / 128) * (NB / 128) * NSPLIT, 256, 0, stream>>>(x, g, pwb, out);
}